// Round 1
// baseline (2647.027 us; speedup 1.0000x reference)
//
#include <hip/hip_runtime.h>
#include <math.h>

namespace {

constexpr int NC  = 64;    // coarse samples
constexpr int NF  = 128;   // fine (importance) samples
constexpr int NT  = NC + NF; // 192 total fine-pass samples
constexpr int HID = 128;
constexpr float T_NEAR = 2.0f, T_FAR = 6.0f;

__device__ __forceinline__ float wave_iscan_mul(float v, int lane) {
  // inclusive prefix product across 64 lanes
  #pragma unroll
  for (int s = 1; s < 64; s <<= 1) {
    float q = __shfl_up(v, s);
    if (lane >= s) v *= q;
  }
  return v;
}

__device__ __forceinline__ float wave_sum(float v) {
  #pragma unroll
  for (int s = 32; s; s >>= 1) v += __shfl_xor(v, s);
  return v;
}

struct MlpOut { float sigma, r, g, b; };

__device__ __forceinline__ MlpOut mlp_eval(
    float px, float py, float pz,
    float dx, float dy, float dz,
    const float* __restrict__ W1, const float* __restrict__ b1,
    const float* __restrict__ W2, const float* __restrict__ b2,
    const float* __restrict__ Wsig, const float* __restrict__ bsig,
    const float* __restrict__ Wrgb, const float* __restrict__ brgb)
{
  float acc[HID];
  #pragma unroll
  for (int o = 0; o < HID; ++o) acc[o] = b2[o];

  // k-loop: recompute h1[k] on the fly (3 FMA), stream W2 row k (contiguous,
  // wave-uniform address -> scalar loads), 128 v_fmac into register acc.
  for (int k = 0; k < HID; ++k) {
    float h1 = fmaf(W1[2 * HID + k], pz,
               fmaf(W1[HID + k],     py,
               fmaf(W1[k],           px, b1[k])));
    h1 = fmaxf(h1, 0.0f);
    const float* __restrict__ w2row = W2 + k * HID;
    #pragma unroll
    for (int o = 0; o < HID; ++o)
      acc[o] = fmaf(h1, w2row[o], acc[o]);
  }

  float s  = bsig[0];
  float r  = brgb[0], g = brgb[1], bb = brgb[2];
  #pragma unroll
  for (int o = 0; o < HID; ++o) {
    float h2 = fmaxf(acc[o], 0.0f);
    s  = fmaf(h2, Wsig[o],       s);
    r  = fmaf(h2, Wrgb[o * 3 + 0], r);
    g  = fmaf(h2, Wrgb[o * 3 + 1], g);
    bb = fmaf(h2, Wrgb[o * 3 + 2], bb);
  }
  // direction rows of Wrgb (rows 128..130)
  r  = fmaf(dx, Wrgb[384], fmaf(dy, Wrgb[387], fmaf(dz, Wrgb[390], r)));
  g  = fmaf(dx, Wrgb[385], fmaf(dy, Wrgb[388], fmaf(dz, Wrgb[391], g)));
  bb = fmaf(dx, Wrgb[386], fmaf(dy, Wrgb[389], fmaf(dz, Wrgb[392], bb)));

  MlpOut out;
  out.sigma = fmaxf(s, 0.0f);
  out.r = 1.0f / (1.0f + expf(-r));
  out.g = 1.0f / (1.0f + expf(-g));
  out.b = 1.0f / (1.0f + expf(-bb));
  return out;
}

__global__ __launch_bounds__(64) void nerf_fused(
    const float* __restrict__ rays_o, const float* __restrict__ rays_d,
    const float* __restrict__ rand_coarse, const float* __restrict__ u_fine,
    const float* __restrict__ W1, const float* __restrict__ b1,
    const float* __restrict__ W2, const float* __restrict__ b2,
    const float* __restrict__ Wsig, const float* __restrict__ bsig,
    const float* __restrict__ Wrgb, const float* __restrict__ brgb,
    float* __restrict__ out, int nrays)
{
  const int b    = blockIdx.x;
  const int lane = threadIdx.x; // 0..63, one wave per block/ray
  if (b >= nrays) return;

  __shared__ float s_e[NT];       // [0:64) t_c ; [64:192) t_mid
  __shared__ float s_tf[NT];      // sorted fine t
  __shared__ float s_cdf[NC + 1];

  const float ox = rays_o[b * 3 + 0], oy = rays_o[b * 3 + 1], oz = rays_o[b * 3 + 2];
  const float dx = rays_d[b * 3 + 0], dy = rays_d[b * 3 + 1], dz = rays_d[b * 3 + 2];

  // ---------------- coarse stratified sampling ----------------
  const float step = (T_FAR - T_NEAR) / (float)(NC - 1);
  const float tl   = T_NEAR + step * (float)lane;
  const float tlp  = T_NEAR + step * (float)(lane - 1);
  const float tln  = T_NEAR + step * (float)(lane + 1);
  const float lower = (lane == 0)      ? tl : 0.5f * (tlp + tl);
  const float upper = (lane == NC - 1) ? tl : 0.5f * (tl + tln);
  const float t = lower + (upper - lower) * rand_coarse[b * NC + lane];

  MlpOut mc = mlp_eval(ox + dx * t, oy + dy * t, oz + dz * t,
                       dx, dy, dz, W1, b1, W2, b2, Wsig, bsig, Wrgb, brgb);

  // ---------------- coarse volume rendering ----------------
  float tnext = __shfl_down(t, 1);
  float delta = (lane == NC - 1) ? 1e10f : (tnext - t);
  float alpha = 1.0f - expf(-mc.sigma * delta);
  float fac   = 1.0f - alpha + 1e-10f;

  float ip = wave_iscan_mul(fac, lane);
  float T  = __shfl_up(ip, 1);
  if (lane == 0) T = 1.0f;
  float w = T * alpha;

  float cr = wave_sum(w * mc.r);
  float cg = wave_sum(w * mc.g);
  float cb = wave_sum(w * mc.b);
  if (lane == 0) {
    out[b * 3 + 0] = cr;
    out[b * 3 + 1] = cg;
    out[b * 3 + 2] = cb;
  }

  s_e[lane] = t;

  // ---------------- importance sampling (cdf + searchsorted) ----------------
  float wp   = w + 1e-5f;
  float wsum = wave_sum(wp);
  float pdf  = wp / wsum;
  float csum = pdf;
  #pragma unroll
  for (int s = 1; s < 64; s <<= 1) {
    float q = __shfl_up(csum, s);
    if (lane >= s) csum += q;
  }
  if (lane == 0) s_cdf[0] = 0.0f;
  s_cdf[lane + 1] = csum;
  __syncthreads();

  #pragma unroll
  for (int h = 0; h < 2; ++h) {
    float u = u_fine[b * NF + h * 64 + lane];
    int ind = 0;
    for (int j = 0; j < NC + 1; ++j)
      ind += (s_cdf[j] <= u) ? 1 : 0;   // searchsorted side='right'
    int below = ind - 1; if (below < 0) below = 0; if (below > NC - 1) below = NC - 1;
    int above = ind;     if (above > NC - 1) above = NC - 1;
    float tmid = 0.5f * (s_e[below] + s_e[above]);
    s_e[NC + h * 64 + lane] = tmid;
  }
  __syncthreads();

  // ---------------- sort 192 t values by rank (stable) ----------------
  #pragma unroll
  for (int q = 0; q < 3; ++q) {
    int j = lane + q * 64;
    float x = s_e[j];
    int rank = 0;
    for (int m = 0; m < NT; ++m) {
      float y = s_e[m];
      rank += (y < x || (y == x && m < j)) ? 1 : 0;
    }
    s_tf[rank] = x;
  }
  __syncthreads();

  // ---------------- fine render: 3 contiguous samples per lane ----------------
  float tq[3], rr[3], gg[3], bbv[3], al[3], fc[3];
  #pragma unroll
  for (int q = 0; q < 3; ++q) {
    int sidx = 3 * lane + q;
    float tf_ = s_tf[sidx];
    tq[q] = tf_;
    MlpOut m = mlp_eval(ox + dx * tf_, oy + dy * tf_, oz + dz * tf_,
                        dx, dy, dz, W1, b1, W2, b2, Wsig, bsig, Wrgb, brgb);
    rr[q] = m.r; gg[q] = m.g; bbv[q] = m.b;
    float dlt = (sidx == NT - 1) ? 1e10f : (s_tf[sidx + 1] - tf_);
    al[q] = 1.0f - expf(-m.sigma * dlt);
    fc[q] = 1.0f - al[q] + 1e-10f;
  }

  float pl  = fc[0] * fc[1] * fc[2];
  float ipf = wave_iscan_mul(pl, lane);
  float P   = __shfl_up(ipf, 1);
  if (lane == 0) P = 1.0f;

  float w0 = P * al[0];
  float w1 = P * fc[0] * al[1];
  float w2 = P * fc[0] * fc[1] * al[2];

  float cfr = wave_sum(fmaf(w0, rr[0],  fmaf(w1, rr[1],  w2 * rr[2])));
  float cfg = wave_sum(fmaf(w0, gg[0],  fmaf(w1, gg[1],  w2 * gg[2])));
  float cfb = wave_sum(fmaf(w0, bbv[0], fmaf(w1, bbv[1], w2 * bbv[2])));
  float dep = wave_sum(fmaf(w0, tq[0],  fmaf(w1, tq[1],  w2 * tq[2])));

  if (lane == 0) {
    out[nrays * 3 + b * 3 + 0] = cfr;
    out[nrays * 3 + b * 3 + 1] = cfg;
    out[nrays * 3 + b * 3 + 2] = cfb;
    out[nrays * 6 + b]         = dep;
  }
}

} // anonymous namespace

extern "C" void kernel_launch(void* const* d_in, const int* in_sizes, int n_in,
                              void* d_out, int out_size, void* d_ws, size_t ws_size,
                              hipStream_t stream) {
  const float* rays_o      = (const float*)d_in[0];
  const float* rays_d      = (const float*)d_in[1];
  const float* rand_coarse = (const float*)d_in[2];
  const float* u_fine      = (const float*)d_in[3];
  const float* W1   = (const float*)d_in[4];
  const float* b1   = (const float*)d_in[5];
  const float* W2   = (const float*)d_in[6];
  const float* b2   = (const float*)d_in[7];
  const float* Wsig = (const float*)d_in[8];
  const float* bsig = (const float*)d_in[9];
  const float* Wrgb = (const float*)d_in[10];
  const float* brgb = (const float*)d_in[11];
  float* out = (float*)d_out;

  const int nrays = in_sizes[0] / 3;

  hipLaunchKernelGGL(nerf_fused, dim3(nrays), dim3(64), 0, stream,
                     rays_o, rays_d, rand_coarse, u_fine,
                     W1, b1, W2, b2, Wsig, bsig, Wrgb, brgb,
                     out, nrays);
}

// Round 2
// 343.808 us; speedup vs baseline: 7.6991x; 7.6991x over previous
//
#include <hip/hip_runtime.h>
#include <math.h>

namespace {

constexpr int NC  = 64;      // coarse samples
constexpr int NF  = 128;     // fine (importance) samples
constexpr int NT  = NC + NF; // 192 total fine-pass samples
constexpr int HID = 128;
constexpr float T_NEAR = 2.0f, T_FAR = 6.0f;
constexpr int RPB = 4;       // rays per (persistent) block

typedef __attribute__((ext_vector_type(8)))  short bf16x8;   // 8 bf16 = 4 VGPRs
typedef __attribute__((ext_vector_type(16))) float f32x16;   // MFMA 32x32 acc
typedef __attribute__((ext_vector_type(4)))  unsigned int u32x4;
typedef __attribute__((ext_vector_type(2)))  __bf16 vbf2;

__device__ __forceinline__ unsigned int pk2(float a, float b) {
  vbf2 t; t[0] = (__bf16)a; t[1] = (__bf16)b;   // RNE cvt; compiler emits v_cvt_pk_bf16_f32
  return __builtin_bit_cast(unsigned int, t);
}
__device__ __forceinline__ bf16x8 mk4(unsigned int w0, unsigned int w1,
                                      unsigned int w2, unsigned int w3) {
  u32x4 u = {w0, w1, w2, w3};
  return __builtin_bit_cast(bf16x8, u);
}
__device__ __forceinline__ f32x16 zero16() {
  f32x16 z;
  #pragma unroll
  for (int i = 0; i < 16; ++i) z[i] = 0.f;
  return z;
}
__device__ __forceinline__ f32x16 mfma(bf16x8 a, bf16x8 b, f32x16 c) {
  return __builtin_amdgcn_mfma_f32_32x32x16_bf16(a, b, c, 0, 0, 0);
}

// h^T acc tile (C layout: col=lane&31=sample, row=(r&3)+8*(r>>2)+4*(lane>>5))
// -> relu -> two B-fragments (ksteps covering local rows 0-15 and 16-31).
__device__ __forceinline__ void cvt_bfrag(const f32x16& a, bool lo,
                                          bf16x8& bE, bf16x8& bO) {
  float v[16];
  #pragma unroll
  for (int r = 0; r < 16; ++r) v[r] = fmaxf(a[r], 0.f);
  unsigned int p0 = pk2(v[0], v[1]),  p1 = pk2(v[2], v[3]);
  unsigned int p2 = pk2(v[4], v[5]),  p3 = pk2(v[6], v[7]);
  unsigned int p4 = pk2(v[8], v[9]),  p5 = pk2(v[10], v[11]);
  unsigned int p6 = pk2(v[12], v[13]), p7 = pk2(v[14], v[15]);
  unsigned int x0 = __shfl_xor((int)p0, 32), x1 = __shfl_xor((int)p1, 32);
  unsigned int x2 = __shfl_xor((int)p2, 32), x3 = __shfl_xor((int)p3, 32);
  unsigned int x4 = __shfl_xor((int)p4, 32), x5 = __shfl_xor((int)p5, 32);
  unsigned int x6 = __shfl_xor((int)p6, 32), x7 = __shfl_xor((int)p7, 32);
  // kstep even: lo lanes rows 0-7, hi lanes rows 8-15
  bE = mk4(lo ? p0 : x2, lo ? p1 : x3, lo ? x0 : p2, lo ? x1 : p3);
  // kstep odd: lo rows 16-23, hi rows 24-31
  bO = mk4(lo ? p4 : x6, lo ? p5 : x7, lo ? x4 : p6, lo ? x5 : p7);
}

struct Wfrag {
  bf16x8 a1[4];     // W1ext^T [hid][k: x,y,z,b1,0..]   4 M-tiles x 1 kstep
  bf16x8 a2[4][9];  // W2ext^T [hid2][k: h1(128), b2, 0..] 4 M-tiles x 9 ksteps
  bf16x8 ah[9];     // head^T  [c: sig,r,g,b,0..][k: h2(128), dirs(3), bias]
  bf16x8 bOne;      // B kstep8 of layer2: k=128 -> 1.0
};

__device__ __forceinline__ void load_weights(Wfrag& w, int lane,
    const float* __restrict__ W1,  const float* __restrict__ b1,
    const float* __restrict__ W2,  const float* __restrict__ b2,
    const float* __restrict__ Wsg, const float* __restrict__ bsg,
    const float* __restrict__ Wrg, const float* __restrict__ brg) {
  const int hl = lane & 31;
  const int hb = (lane >> 5) * 8;      // k-offset of this lane half
  const bool lo = (lane < 32);

  #pragma unroll
  for (int m = 0; m < 4; ++m) {
    int h = 32 * m + hl;
    w.a1[m] = lo ? mk4(pk2(W1[h], W1[HID + h]), pk2(W1[2 * HID + h], b1[h]), 0u, 0u)
                 : mk4(0u, 0u, 0u, 0u);
  }
  #pragma unroll
  for (int m = 0; m < 4; ++m) {
    int h = 32 * m + hl;
    #pragma unroll
    for (int k9 = 0; k9 < 9; ++k9) {
      float e[8];
      #pragma unroll
      for (int i = 0; i < 8; ++i) {
        int kk = 16 * k9 + hb + i;
        e[i] = (kk < 128) ? W2[kk * HID + h] : ((kk == 128) ? b2[h] : 0.f);
      }
      w.a2[m][k9] = mk4(pk2(e[0], e[1]), pk2(e[2], e[3]),
                        pk2(e[4], e[5]), pk2(e[6], e[7]));
    }
  }
  const int c = hl;
  #pragma unroll
  for (int k9 = 0; k9 < 9; ++k9) {
    float e[8];
    #pragma unroll
    for (int i = 0; i < 8; ++i) {
      int kk = 16 * k9 + hb + i;
      float v = 0.f;
      if (c == 0)       { if (kk < 128) v = Wsg[kk]; else if (kk == 131) v = bsg[0]; }
      else if (c <= 3)  { if (kk < 131) v = Wrg[kk * 3 + (c - 1)]; else if (kk == 131) v = brg[c - 1]; }
      e[i] = v;
    }
    w.ah[k9] = mk4(pk2(e[0], e[1]), pk2(e[2], e[3]),
                   pk2(e[4], e[5]), pk2(e[6], e[7]));
  }
  w.bOne = lo ? mk4(pk2(1.f, 0.f), 0u, 0u, 0u) : mk4(0u, 0u, 0u, 0u);
}

// One 32-sample tile through the MLP. Valid outputs land in lanes 0-31
// (lane s holds sample s of this tile).
__device__ __forceinline__ void mlp_tile(const Wfrag& w, float ts,
    float ox, float oy, float oz, float dxx, float dyy, float dzz,
    bf16x8 dirB, int lane,
    float& osig, float& oR, float& oG, float& oB) {
  const bool lo = (lane < 32);
  float px = fmaf(dxx, ts, ox), py = fmaf(dyy, ts, oy), pz = fmaf(dzz, ts, oz);
  bf16x8 bP = lo ? mk4(pk2(px, py), pk2(pz, 1.f), 0u, 0u) : mk4(0u, 0u, 0u, 0u);

  // layer 1: h1^T = W1ext^T @ [pts;1]^T   (single kstep, K=4 used)
  bf16x8 bH[9];
  #pragma unroll
  for (int m = 0; m < 4; ++m) {
    f32x16 acc = mfma(w.a1[m], bP, zero16());
    cvt_bfrag(acc, lo, bH[2 * m], bH[2 * m + 1]);
  }
  bH[8] = w.bOne;

  // layer 2: h2^T = W2ext^T @ [h1;1]^T
  bf16x8 bH2[9];
  #pragma unroll
  for (int m = 0; m < 4; ++m) {
    f32x16 acc = zero16();
    #pragma unroll
    for (int k = 0; k < 9; ++k) acc = mfma(w.a2[m][k], bH[k], acc);
    cvt_bfrag(acc, lo, bH2[2 * m], bH2[2 * m + 1]);
  }
  bH2[8] = dirB;

  // head: [sigma,r,g,b]^T = Whead^T @ [h2; dirs; 1]^T
  f32x16 acch = zero16();
  #pragma unroll
  for (int k = 0; k < 9; ++k) acch = mfma(w.ah[k], bH2[k], acch);

  osig = fmaxf(acch[0], 0.f);
  oR = 1.f / (1.f + expf(-acch[1]));
  oG = 1.f / (1.f + expf(-acch[2]));
  oB = 1.f / (1.f + expf(-acch[3]));
}

__global__ __launch_bounds__(64, 1) void nerf_mfma(
    const float* __restrict__ rays_o, const float* __restrict__ rays_d,
    const float* __restrict__ rand_coarse, const float* __restrict__ u_fine,
    const float* __restrict__ W1, const float* __restrict__ b1,
    const float* __restrict__ W2, const float* __restrict__ b2,
    const float* __restrict__ Wsg, const float* __restrict__ bsg,
    const float* __restrict__ Wrg, const float* __restrict__ brg,
    float* __restrict__ out, int nrays)
{
  const int lane = threadIdx.x;

  __shared__ float  s_e[NT];
  __shared__ float  s_tf[NT];
  __shared__ float  s_cdf[NC + 1];
  __shared__ float4 s_out[NT];

  Wfrag w;
  load_weights(w, lane, W1, b1, W2, b2, Wsg, bsg, Wrg, brg);

  for (int rr = 0; rr < RPB; ++rr) {
    const int b = blockIdx.x * RPB + rr;
    if (b >= nrays) break;
    __syncthreads();

    const float ox = rays_o[b * 3 + 0], oy = rays_o[b * 3 + 1], oz = rays_o[b * 3 + 2];
    const float dxx = rays_d[b * 3 + 0], dyy = rays_d[b * 3 + 1], dzz = rays_d[b * 3 + 2];
    const bf16x8 dirB = (lane < 32) ? mk4(pk2(dxx, dyy), pk2(dzz, 1.f), 0u, 0u)
                                    : mk4(0u, 0u, 0u, 0u);

    // ---------------- coarse stratified sampling ----------------
    const float step = (T_FAR - T_NEAR) / (float)(NC - 1);
    const float tl  = T_NEAR + step * (float)lane;
    const float tlp = T_NEAR + step * (float)(lane - 1);
    const float tln = T_NEAR + step * (float)(lane + 1);
    const float lower = (lane == 0)      ? tl : 0.5f * (tlp + tl);
    const float upper = (lane == NC - 1) ? tl : 0.5f * (tl + tln);
    const float t = lower + (upper - lower) * rand_coarse[b * NC + lane];

    // ---------------- coarse MLP (2 tiles of 32 samples) ----------------
    for (int tau = 0; tau < 2; ++tau) {
      float ts = __shfl(t, tau * 32 + (lane & 31));
      float sg, r_, g_, b_;
      mlp_tile(w, ts, ox, oy, oz, dxx, dyy, dzz, dirB, lane, sg, r_, g_, b_);
      if (lane < 32) s_out[tau * 32 + lane] = make_float4(sg, r_, g_, b_);
    }
    __syncthreads();
    float4 o4 = s_out[lane];
    float sig = o4.x, mr = o4.y, mg = o4.z, mb = o4.w;

    // ---------------- coarse volume rendering ----------------
    float tnext = __shfl_down(t, 1);
    float delta = (lane == NC - 1) ? 1e10f : (tnext - t);
    float alpha = 1.0f - expf(-sig * delta);
    float fac   = 1.0f - alpha + 1e-10f;

    float ip = fac;
    #pragma unroll
    for (int s = 1; s < 64; s <<= 1) {
      float q = __shfl_up(ip, s);
      if (lane >= s) ip *= q;
    }
    float T = __shfl_up(ip, 1);
    if (lane == 0) T = 1.0f;
    float wgt = T * alpha;

    float cr = wgt * mr, cg = wgt * mg, cb = wgt * mb;
    #pragma unroll
    for (int s = 32; s; s >>= 1) {
      cr += __shfl_xor(cr, s); cg += __shfl_xor(cg, s); cb += __shfl_xor(cb, s);
    }
    if (lane == 0) {
      out[b * 3 + 0] = cr; out[b * 3 + 1] = cg; out[b * 3 + 2] = cb;
    }

    s_e[lane] = t;

    // ---------------- importance sampling ----------------
    float wp = wgt + 1e-5f;
    float wsum = wp;
    #pragma unroll
    for (int s = 32; s; s >>= 1) wsum += __shfl_xor(wsum, s);
    float pdf = wp / wsum;
    float csum = pdf;
    #pragma unroll
    for (int s = 1; s < 64; s <<= 1) {
      float q = __shfl_up(csum, s);
      if (lane >= s) csum += q;
    }
    if (lane == 0) s_cdf[0] = 0.0f;
    s_cdf[lane + 1] = csum;
    __syncthreads();

    #pragma unroll
    for (int h = 0; h < 2; ++h) {
      float u = u_fine[b * NF + h * 64 + lane];
      int ind = 0;
      for (int j = 0; j < NC + 1; ++j)
        ind += (s_cdf[j] <= u) ? 1 : 0;     // searchsorted side='right'
      int below = ind - 1; if (below < 0) below = 0; if (below > NC - 1) below = NC - 1;
      int above = ind;     if (above > NC - 1) above = NC - 1;
      s_e[NC + h * 64 + lane] = 0.5f * (s_e[below] + s_e[above]);
    }
    __syncthreads();

    // ---------------- rank sort of 192 t values (stable) ----------------
    #pragma unroll
    for (int q = 0; q < 3; ++q) {
      int j = lane + q * 64;
      float x = s_e[j];
      int rank = 0;
      for (int m = 0; m < NT; ++m) {
        float y = s_e[m];
        rank += (y < x || (y == x && m < j)) ? 1 : 0;
      }
      s_tf[rank] = x;
    }
    __syncthreads();

    // ---------------- fine MLP (6 tiles of 32 samples) ----------------
    for (int tau = 0; tau < 6; ++tau) {
      float ts = s_tf[tau * 32 + (lane & 31)];
      float sg, r_, g_, b_;
      mlp_tile(w, ts, ox, oy, oz, dxx, dyy, dzz, dirB, lane, sg, r_, g_, b_);
      if (lane < 32) s_out[tau * 32 + lane] = make_float4(sg, r_, g_, b_);
    }
    __syncthreads();

    // ---------------- fine render: 3 contiguous samples per lane ----------------
    float tq[3], rr2[3], gg[3], bb2[3], al[3], fc[3];
    #pragma unroll
    for (int q = 0; q < 3; ++q) {
      int sidx = 3 * lane + q;
      float tf_ = s_tf[sidx];
      float4 m4 = s_out[sidx];
      tq[q] = tf_; rr2[q] = m4.y; gg[q] = m4.z; bb2[q] = m4.w;
      float dlt = (sidx == NT - 1) ? 1e10f : (s_tf[sidx + 1] - tf_);
      al[q] = 1.0f - expf(-m4.x * dlt);
      fc[q] = 1.0f - al[q] + 1e-10f;
    }

    float pl = fc[0] * fc[1] * fc[2];
    float ipf = pl;
    #pragma unroll
    for (int s = 1; s < 64; s <<= 1) {
      float q = __shfl_up(ipf, s);
      if (lane >= s) ipf *= q;
    }
    float P = __shfl_up(ipf, 1);
    if (lane == 0) P = 1.0f;

    float w0 = P * al[0];
    float w1 = P * fc[0] * al[1];
    float w2 = P * fc[0] * fc[1] * al[2];

    float cfr = fmaf(w0, rr2[0], fmaf(w1, rr2[1], w2 * rr2[2]));
    float cfg = fmaf(w0, gg[0],  fmaf(w1, gg[1],  w2 * gg[2]));
    float cfb = fmaf(w0, bb2[0], fmaf(w1, bb2[1], w2 * bb2[2]));
    float dep = fmaf(w0, tq[0],  fmaf(w1, tq[1],  w2 * tq[2]));
    #pragma unroll
    for (int s = 32; s; s >>= 1) {
      cfr += __shfl_xor(cfr, s); cfg += __shfl_xor(cfg, s);
      cfb += __shfl_xor(cfb, s); dep += __shfl_xor(dep, s);
    }

    if (lane == 0) {
      out[nrays * 3 + b * 3 + 0] = cfr;
      out[nrays * 3 + b * 3 + 1] = cfg;
      out[nrays * 3 + b * 3 + 2] = cfb;
      out[nrays * 6 + b]         = dep;
    }
  }
}

} // anonymous namespace

extern "C" void kernel_launch(void* const* d_in, const int* in_sizes, int n_in,
                              void* d_out, int out_size, void* d_ws, size_t ws_size,
                              hipStream_t stream) {
  const float* rays_o      = (const float*)d_in[0];
  const float* rays_d      = (const float*)d_in[1];
  const float* rand_coarse = (const float*)d_in[2];
  const float* u_fine      = (const float*)d_in[3];
  const float* W1   = (const float*)d_in[4];
  const float* b1   = (const float*)d_in[5];
  const float* W2   = (const float*)d_in[6];
  const float* b2   = (const float*)d_in[7];
  const float* Wsig = (const float*)d_in[8];
  const float* bsig = (const float*)d_in[9];
  const float* Wrgb = (const float*)d_in[10];
  const float* brgb = (const float*)d_in[11];
  float* out = (float*)d_out;

  const int nrays = in_sizes[0] / 3;
  const int grid  = (nrays + RPB - 1) / RPB;

  hipLaunchKernelGGL(nerf_mfma, dim3(grid), dim3(64), 0, stream,
                     rays_o, rays_d, rand_coarse, u_fine,
                     W1, b1, W2, b2, Wsig, bsig, Wrgb, brgb,
                     out, nrays);
}

// Round 4
// 155.505 us; speedup vs baseline: 17.0221x; 2.2109x over previous
//
#include <hip/hip_runtime.h>
#include <math.h>

namespace {

constexpr int NC  = 64;      // coarse samples
constexpr int NF  = 128;     // fine (importance) samples
constexpr int NT  = NC + NF; // 192 total fine-pass samples
constexpr int HID = 128;
constexpr float T_NEAR = 2.0f, T_FAR = 6.0f;
constexpr int RPB = 4;       // rays per block

typedef __attribute__((ext_vector_type(8)))  short bf16x8;   // 8 bf16 = 4 VGPRs
typedef __attribute__((ext_vector_type(16))) float f32x16;   // MFMA 32x32 acc
typedef __attribute__((ext_vector_type(4)))  unsigned int u32x4;
typedef __attribute__((ext_vector_type(2)))  __bf16 vbf2;

__device__ __forceinline__ unsigned int pk2(float a, float b) {
  vbf2 t; t[0] = (__bf16)a; t[1] = (__bf16)b;   // v_cvt_pk_bf16_f32
  return __builtin_bit_cast(unsigned int, t);
}
__device__ __forceinline__ bf16x8 mk4(unsigned int w0, unsigned int w1,
                                      unsigned int w2, unsigned int w3) {
  u32x4 u = {w0, w1, w2, w3};
  return __builtin_bit_cast(bf16x8, u);
}
__device__ __forceinline__ f32x16 zero16() {
  f32x16 z;
  #pragma unroll
  for (int i = 0; i < 16; ++i) z[i] = 0.f;
  return z;
}
__device__ __forceinline__ f32x16 mfma(bf16x8 a, bf16x8 b, f32x16 c) {
  return __builtin_amdgcn_mfma_f32_32x32x16_bf16(a, b, c, 0, 0, 0);
}

// k-slot permutation: slot (k9,hi,i) of the B operand holds, in-lane, the
// C-tile register r of the producing layer. pi(kslot) = source-row index.
// pi(k) = 32*(k9>>1) + 16*(k9&1) + 4*hi + (i&3) + 8*(i>>2); bijection on 0..127.
// A-fragments (W2, Whead) are loaded pre-permuted by pi so B needs NO
// cross-lane exchange: bE/bO are just relu+pack of acc[0..7] / acc[8..15].
__device__ __forceinline__ int kperm(int k9, int hi, int i) {
  return 32 * (k9 >> 1) + 16 * (k9 & 1) + 4 * hi + (i & 3) + 8 * (i >> 2);
}

// acc C-tile -> relu -> two B-fragment ksteps, pure in-lane VALU.
__device__ __forceinline__ void cvt_direct(const f32x16& a, bf16x8& bE, bf16x8& bO) {
  float v[16];
  #pragma unroll
  for (int r = 0; r < 16; ++r) v[r] = fmaxf(a[r], 0.f);
  bE = mk4(pk2(v[0],  v[1]),  pk2(v[2],  v[3]),
           pk2(v[4],  v[5]),  pk2(v[6],  v[7]));
  bO = mk4(pk2(v[8],  v[9]),  pk2(v[10], v[11]),
           pk2(v[12], v[13]), pk2(v[14], v[15]));
}

struct Wfrag {
  bf16x8 a1[4];     // W1ext^T [hid][k: x,y,z,b1] (no perm; B built manually)
  bf16x8 a2[4][9];  // W2ext^T, k<128 pi-permuted; k9=8: k=128 -> b2
  bf16x8 ah[9];     // head^T,  k<128 pi-permuted; k9=8: dirs(128..130), bias(131)
  bf16x8 bOne;      // B kstep8 of layer2: slot 128 -> 1.0
};

__device__ __forceinline__ void load_weights(Wfrag& w, int lane,
    const float* __restrict__ W1,  const float* __restrict__ b1,
    const float* __restrict__ W2,  const float* __restrict__ b2,
    const float* __restrict__ Wsg, const float* __restrict__ bsg,
    const float* __restrict__ Wrg, const float* __restrict__ brg) {
  const int hl = lane & 31;
  const int hi = lane >> 5;
  const bool lo = (lane < 32);

  #pragma unroll
  for (int m = 0; m < 4; ++m) {
    int h = 32 * m + hl;
    w.a1[m] = lo ? mk4(pk2(W1[h], W1[HID + h]), pk2(W1[2 * HID + h], b1[h]), 0u, 0u)
                 : mk4(0u, 0u, 0u, 0u);
  }
  #pragma unroll
  for (int m = 0; m < 4; ++m) {
    int h = 32 * m + hl;
    #pragma unroll
    for (int k9 = 0; k9 < 9; ++k9) {
      float e[8];
      #pragma unroll
      for (int i = 0; i < 8; ++i) {
        if (k9 < 8) {
          e[i] = W2[kperm(k9, hi, i) * HID + h];
        } else {
          int kk = 128 + 8 * hi + i;
          e[i] = (kk == 128) ? b2[h] : 0.f;
        }
      }
      w.a2[m][k9] = mk4(pk2(e[0], e[1]), pk2(e[2], e[3]),
                        pk2(e[4], e[5]), pk2(e[6], e[7]));
    }
  }
  const int c = hl;
  #pragma unroll
  for (int k9 = 0; k9 < 9; ++k9) {
    float e[8];
    #pragma unroll
    for (int i = 0; i < 8; ++i) {
      int kk = (k9 < 8) ? kperm(k9, hi, i) : (128 + 8 * hi + i);
      float v = 0.f;
      if (c == 0)       { if (kk < 128) v = Wsg[kk]; else if (kk == 131) v = bsg[0]; }
      else if (c <= 3)  { if (kk < 131) v = Wrg[kk * 3 + (c - 1)]; else if (kk == 131) v = brg[c - 1]; }
      e[i] = v;
    }
    w.ah[k9] = mk4(pk2(e[0], e[1]), pk2(e[2], e[3]),
                   pk2(e[4], e[5]), pk2(e[6], e[7]));
  }
  w.bOne = lo ? mk4(pk2(1.f, 0.f), 0u, 0u, 0u) : mk4(0u, 0u, 0u, 0u);
}

__device__ __forceinline__ float sigm(float x) { return 1.f / (1.f + __expf(-x)); }

// Two 32-sample tiles through the MLP (independent MFMA chains interleaved).
// Valid outputs land in lanes 0-31 (lane s = sample s of each tile).
__device__ __forceinline__ void mlp_tile2(const Wfrag& w, float tsA, float tsB,
    float ox, float oy, float oz, float dxx, float dyy, float dzz,
    bf16x8 dirB, int lane, float4& outA, float4& outB) {
  const bool lo = (lane < 32);
  float pxA = fmaf(dxx, tsA, ox), pyA = fmaf(dyy, tsA, oy), pzA = fmaf(dzz, tsA, oz);
  float pxB = fmaf(dxx, tsB, ox), pyB = fmaf(dyy, tsB, oy), pzB = fmaf(dzz, tsB, oz);
  bf16x8 bPA = lo ? mk4(pk2(pxA, pyA), pk2(pzA, 1.f), 0u, 0u) : mk4(0u, 0u, 0u, 0u);
  bf16x8 bPB = lo ? mk4(pk2(pxB, pyB), pk2(pzB, 1.f), 0u, 0u) : mk4(0u, 0u, 0u, 0u);

  // layer 1
  bf16x8 bHA[9], bHB[9];
  #pragma unroll
  for (int m = 0; m < 4; ++m) {
    f32x16 aA = mfma(w.a1[m], bPA, zero16());
    f32x16 aB = mfma(w.a1[m], bPB, zero16());
    cvt_direct(aA, bHA[2 * m], bHA[2 * m + 1]);
    cvt_direct(aB, bHB[2 * m], bHB[2 * m + 1]);
  }
  bHA[8] = w.bOne; bHB[8] = w.bOne;

  // layer 2
  bf16x8 b2A[9], b2B[9];
  #pragma unroll
  for (int m = 0; m < 4; ++m) {
    f32x16 aA = zero16(), aB = zero16();
    #pragma unroll
    for (int k = 0; k < 9; ++k) {
      aA = mfma(w.a2[m][k], bHA[k], aA);
      aB = mfma(w.a2[m][k], bHB[k], aB);
    }
    cvt_direct(aA, b2A[2 * m], b2A[2 * m + 1]);
    cvt_direct(aB, b2B[2 * m], b2B[2 * m + 1]);
  }
  b2A[8] = dirB; b2B[8] = dirB;

  // head
  f32x16 hA = zero16(), hB = zero16();
  #pragma unroll
  for (int k = 0; k < 9; ++k) {
    hA = mfma(w.ah[k], b2A[k], hA);
    hB = mfma(w.ah[k], b2B[k], hB);
  }
  outA = make_float4(fmaxf(hA[0], 0.f), sigm(hA[1]), sigm(hA[2]), sigm(hA[3]));
  outB = make_float4(fmaxf(hB[0], 0.f), sigm(hB[1]), sigm(hB[2]), sigm(hB[3]));
}

__global__ __launch_bounds__(64, 1) void nerf_mfma(
    const float* __restrict__ rays_o, const float* __restrict__ rays_d,
    const float* __restrict__ rand_coarse, const float* __restrict__ u_fine,
    const float* __restrict__ W1, const float* __restrict__ b1,
    const float* __restrict__ W2, const float* __restrict__ b2,
    const float* __restrict__ Wsg, const float* __restrict__ bsg,
    const float* __restrict__ Wrg, const float* __restrict__ brg,
    float* __restrict__ out, int nrays)
{
  const int lane = threadIdx.x;

  __shared__ float    s_e[NC];        // coarse t
  __shared__ float    s_tf[NT];       // sorted fine t
  __shared__ float    s_cdf[NC + 1];
  __shared__ int      s_exc[NC + 1];  // exclusive bin prefix
  __shared__ unsigned s_cnt[NC + 1];  // histogram of searchsorted bins
  __shared__ float4   s_out[NT];

  Wfrag w;
  load_weights(w, lane, W1, b1, W2, b2, Wsg, bsg, Wrg, brg);

  for (int rr = 0; rr < RPB; ++rr) {
    const int b = blockIdx.x * RPB + rr;
    if (b >= nrays) break;
    __syncthreads();

    const float ox = rays_o[b * 3 + 0], oy = rays_o[b * 3 + 1], oz = rays_o[b * 3 + 2];
    const float dxx = rays_d[b * 3 + 0], dyy = rays_d[b * 3 + 1], dzz = rays_d[b * 3 + 2];
    const bf16x8 dirB = (lane < 32) ? mk4(pk2(dxx, dyy), pk2(dzz, 1.f), 0u, 0u)
                                    : mk4(0u, 0u, 0u, 0u);

    // ---------------- coarse stratified sampling ----------------
    const float step = (T_FAR - T_NEAR) / (float)(NC - 1);
    const float tl  = T_NEAR + step * (float)lane;
    const float tlp = T_NEAR + step * (float)(lane - 1);
    const float tln = T_NEAR + step * (float)(lane + 1);
    const float lower = (lane == 0)      ? tl : 0.5f * (tlp + tl);
    const float upper = (lane == NC - 1) ? tl : 0.5f * (tl + tln);
    const float t = lower + (upper - lower) * rand_coarse[b * NC + lane];

    // ---------------- coarse MLP (2 tiles, one interleaved call) ----------------
    {
      float tsA = __shfl(t, lane & 31);
      float tsB = __shfl(t, 32 + (lane & 31));
      float4 oA, oB;
      mlp_tile2(w, tsA, tsB, ox, oy, oz, dxx, dyy, dzz, dirB, lane, oA, oB);
      if (lane < 32) {
        s_out[lane]      = oA;   // verified round-2 redistribution (LDS)
        s_out[32 + lane] = oB;
      }
    }
    __syncthreads();
    float4 o4 = s_out[lane];
    float sig = o4.x, mr = o4.y, mg = o4.z, mb = o4.w;

    // ---------------- coarse volume rendering ----------------
    float tnext = __shfl_down(t, 1);
    float delta = (lane == NC - 1) ? 1e10f : (tnext - t);
    float alpha = 1.0f - __expf(-sig * delta);
    float fac   = 1.0f - alpha + 1e-10f;

    float ip = fac;
    #pragma unroll
    for (int s = 1; s < 64; s <<= 1) {
      float q = __shfl_up(ip, s);
      if (lane >= s) ip *= q;
    }
    float T = __shfl_up(ip, 1);
    if (lane == 0) T = 1.0f;
    float wgt = T * alpha;

    float cr = wgt * mr, cg = wgt * mg, cb = wgt * mb;
    #pragma unroll
    for (int s = 32; s; s >>= 1) {
      cr += __shfl_xor(cr, s); cg += __shfl_xor(cg, s); cb += __shfl_xor(cb, s);
    }
    if (lane == 0) {
      out[b * 3 + 0] = cr; out[b * 3 + 1] = cg; out[b * 3 + 2] = cb;
    }

    s_e[lane] = t;
    s_cnt[lane] = 0u;
    if (lane == 0) s_cnt[NC] = 0u;

    // ---------------- importance sampling: cdf ----------------
    float wp = wgt + 1e-5f;
    float wsum = wp;
    #pragma unroll
    for (int s = 32; s; s >>= 1) wsum += __shfl_xor(wsum, s);
    float pdf = wp / wsum;
    float csum = pdf;
    #pragma unroll
    for (int s = 1; s < 64; s <<= 1) {
      float q = __shfl_up(csum, s);
      if (lane >= s) csum += q;
    }
    if (lane == 0) s_cdf[0] = 0.0f;
    s_cdf[lane + 1] = csum;
    __syncthreads();

    // ---------------- searchsorted + histogram (2 u's per lane) ----------------
    int indh[2]; unsigned rh[2];
    #pragma unroll
    for (int h = 0; h < 2; ++h) {
      float u = u_fine[b * NF + h * 64 + lane];
      int ind = 0;
      #pragma unroll
      for (int j = 0; j < NC + 1; ++j)
        ind += (s_cdf[j] <= u) ? 1 : 0;     // side='right'; ind >= 1 (cdf[0]=0)
      if (ind > NC) ind = NC;               // value-equivalent clamp (t_mid == t_c[63])
      indh[h] = ind;
      rh[h] = atomicAdd(&s_cnt[ind], 1u);   // tie rank (equal values -> order irrelevant)
    }
    __syncthreads();

    // ---------------- analytic "sort": prefix over bins + scatter ----------------
    // t_mid of bin b satisfies t_c[b-1] <= t_mid <= t_c[b] (fp midpoint stays in
    // range), so sorted order = t_c[0], mids(1), t_c[1], mids(2), ..., mids(64).
    int c  = (int)s_cnt[lane];
    int ci = c;
    #pragma unroll
    for (int s = 1; s < 64; s <<= 1) {
      int q = __shfl_up(ci, s);
      if (lane >= s) ci += q;
    }
    s_exc[lane] = ci - c;                   // excl prefix of bins 0..63
    if (lane == 63) s_exc[NC] = ci;         // excl prefix of bin 64
    s_tf[lane + ci] = t;                    // t_c[i] -> i + incl_prefix(i)
    __syncthreads();

    #pragma unroll
    for (int h = 0; h < 2; ++h) {
      int ind = indh[h];
      int below = ind - 1; if (below > NC - 1) below = NC - 1;
      int above = ind;     if (above > NC - 1) above = NC - 1;
      float tmid = 0.5f * (s_e[below] + s_e[above]);
      s_tf[ind + s_exc[ind] + (int)rh[h]] = tmid;
    }
    __syncthreads();

    // ---------------- fine MLP (6 tiles = 3 interleaved calls) ----------------
    #pragma unroll
    for (int p = 0; p < 3; ++p) {
      float tsA = s_tf[p * 64 + (lane & 31)];
      float tsB = s_tf[p * 64 + 32 + (lane & 31)];
      float4 fA, fB;
      mlp_tile2(w, tsA, tsB, ox, oy, oz, dxx, dyy, dzz, dirB, lane, fA, fB);
      if (lane < 32) {
        s_out[p * 64 + lane]      = fA;
        s_out[p * 64 + 32 + lane] = fB;
      }
    }
    __syncthreads();

    // ---------------- fine render: 3 contiguous samples per lane ----------------
    float tq[3], rr2[3], gg[3], bb2[3], al[3], fc[3];
    #pragma unroll
    for (int q = 0; q < 3; ++q) {
      int sidx = 3 * lane + q;
      float tf_ = s_tf[sidx];
      float4 m4 = s_out[sidx];
      tq[q] = tf_; rr2[q] = m4.y; gg[q] = m4.z; bb2[q] = m4.w;
      float dlt = (sidx == NT - 1) ? 1e10f : (s_tf[sidx + 1] - tf_);
      al[q] = 1.0f - __expf(-m4.x * dlt);
      fc[q] = 1.0f - al[q] + 1e-10f;
    }

    float pl = fc[0] * fc[1] * fc[2];
    float ipf = pl;
    #pragma unroll
    for (int s = 1; s < 64; s <<= 1) {
      float q = __shfl_up(ipf, s);
      if (lane >= s) ipf *= q;
    }
    float P = __shfl_up(ipf, 1);
    if (lane == 0) P = 1.0f;

    float w0 = P * al[0];
    float w1 = P * fc[0] * al[1];
    float w2 = P * fc[0] * fc[1] * al[2];

    float cfr = fmaf(w0, rr2[0], fmaf(w1, rr2[1], w2 * rr2[2]));
    float cfg = fmaf(w0, gg[0],  fmaf(w1, gg[1],  w2 * gg[2]));
    float cfb = fmaf(w0, bb2[0], fmaf(w1, bb2[1], w2 * bb2[2]));
    float dep = fmaf(w0, tq[0],  fmaf(w1, tq[1],  w2 * tq[2]));
    #pragma unroll
    for (int s = 32; s; s >>= 1) {
      cfr += __shfl_xor(cfr, s); cfg += __shfl_xor(cfg, s);
      cfb += __shfl_xor(cfb, s); dep += __shfl_xor(dep, s);
    }

    if (lane == 0) {
      out[nrays * 3 + b * 3 + 0] = cfr;
      out[nrays * 3 + b * 3 + 1] = cfg;
      out[nrays * 3 + b * 3 + 2] = cfb;
      out[nrays * 6 + b]         = dep;
    }
  }
}

} // anonymous namespace

extern "C" void kernel_launch(void* const* d_in, const int* in_sizes, int n_in,
                              void* d_out, int out_size, void* d_ws, size_t ws_size,
                              hipStream_t stream) {
  const float* rays_o      = (const float*)d_in[0];
  const float* rays_d      = (const float*)d_in[1];
  const float* rand_coarse = (const float*)d_in[2];
  const float* u_fine      = (const float*)d_in[3];
  const float* W1   = (const float*)d_in[4];
  const float* b1   = (const float*)d_in[5];
  const float* W2   = (const float*)d_in[6];
  const float* b2   = (const float*)d_in[7];
  const float* Wsig = (const float*)d_in[8];
  const float* bsig = (const float*)d_in[9];
  const float* Wrgb = (const float*)d_in[10];
  const float* brgb = (const float*)d_in[11];
  float* out = (float*)d_out;

  const int nrays = in_sizes[0] / 3;
  const int grid  = (nrays + RPB - 1) / RPB;

  hipLaunchKernelGGL(nerf_mfma, dim3(grid), dim3(64), 0, stream,
                     rays_o, rays_d, rand_coarse, u_fine,
                     W1, b1, W2, b2, Wsig, bsig, Wrgb, brgb,
                     out, nrays);
}